// Round 5
// baseline (106.389 us; speedup 1.0000x reference)
//
#include <hip/hip_runtime.h>
#include <hip/hip_bf16.h>

typedef __attribute__((ext_vector_type(8))) __bf16 bf16x8;
typedef __attribute__((ext_vector_type(4))) float f32x4;
typedef __attribute__((ext_vector_type(8))) unsigned short ushort8;
typedef __attribute__((ext_vector_type(4))) unsigned short ushort4v;

__device__ __forceinline__ unsigned short f2bf(float f) {
  unsigned u = __builtin_bit_cast(unsigned, f);
  u += 0x7FFFu + ((u >> 16) & 1u);   // round-to-nearest-even
  return (unsigned short)(u >> 16);
}

__device__ __forceinline__ void gload_lds16(const void* g, void* l) {
  __builtin_amdgcn_global_load_lds(
      (const __attribute__((address_space(1))) void*)g,
      (__attribute__((address_space(3))) void*)l, 16, 0, 0);
}

template <int N>
__device__ __forceinline__ void waitvm() {
  if constexpr (N == 0)       asm volatile("s_waitcnt vmcnt(0)" ::: "memory");
  else if constexpr (N == 4)  asm volatile("s_waitcnt vmcnt(4)" ::: "memory");
  else if constexpr (N == 6)  asm volatile("s_waitcnt vmcnt(6)" ::: "memory");
  else if constexpr (N == 8)  asm volatile("s_waitcnt vmcnt(8)" ::: "memory");
  else if constexpr (N == 12) asm volatile("s_waitcnt vmcnt(12)" ::: "memory");
}

__device__ __forceinline__ void barrier_fence() {
  __builtin_amdgcn_s_barrier();
  asm volatile("" ::: "memory");   // no LDS op crosses the barrier at compile time
}

// ---- prep: Ut = bf16(U^T), Wt = bf16(W^T), Vb = bf16(V), one launch ----
__global__ __launch_bounds__(256) void prep_kernel(
    const float* __restrict__ U, unsigned short* __restrict__ Ut,
    const float* __restrict__ W, unsigned short* __restrict__ Wt,
    const float* __restrict__ V, unsigned short* __restrict__ Vb) {
  __shared__ float tile[32][33];
  const int b = blockIdx.x;
  const int tid = threadIdx.x;
  if (b < 2560) {
    const float* src;
    unsigned short* dst;
    int rows, cols, bx, by;
    if (b < 2048) {
      src = U; dst = Ut; rows = 4096; cols = 512;
      bx = (b & 15) * 32; by = (b >> 4) * 32;
    } else {
      int bb = b - 2048;
      src = W; dst = Wt; rows = 1024; cols = 512;
      bx = (bb & 15) * 32; by = (bb >> 4) * 32;
    }
    const int tx = tid & 31, ty = tid >> 5;
    for (int i = ty; i < 32; i += 8)
      tile[i][tx] = src[(size_t)(by + i) * cols + bx + tx];
    __syncthreads();
    for (int i = ty; i < 32; i += 8)
      dst[(size_t)(bx + i) * rows + by + tx] = f2bf(tile[tx][i]);
  } else {
    const size_t i = (size_t)(b - 2560) * 256 + tid;  // 8 f32 per thread
    const float4* s4 = reinterpret_cast<const float4*>(V) + 2 * i;
    float4 a = s4[0], c = s4[1];
    ushort8 o;
    o[0] = f2bf(a.x); o[1] = f2bf(a.y); o[2] = f2bf(a.z); o[3] = f2bf(a.w);
    o[4] = f2bf(c.x); o[5] = f2bf(c.y); o[6] = f2bf(c.z); o[7] = f2bf(c.w);
    *(reinterpret_cast<ushort8*>(Vb) + i) = o;
  }
}

// ------------- 64x64 GEMM tile, depth-3 counted-vmcnt pipeline -------------
// C[64,64] = A[64,K] * Bt[64,K]^T.  A f32 (staged raw, cvt on read) or bf16.
// B always bf16.  3 LDS buffers; per step: vmcnt(2*ISS) -> barrier ->
// compute -> lgkmcnt(0) -> barrier -> stage(t+3).  vmcnt never drains to 0
// in the main loop (T3+T4).
// EPI 2: outf[idx] = relu(acc + e0[col]); EPI 3: outf[idx] = acc (partial).
template <int EPI, bool AF32>
__device__ __forceinline__ void gemm_core_pipe(
    const void* __restrict__ Av, const unsigned short* __restrict__ Bt,
    int N, int lda, int kchunk, int k0, const float* __restrict__ e0,
    float* __restrict__ outf) {
  constexpr int BK = 64;
  constexpr int ABYTES = 64 * BK * (AF32 ? 4 : 2);
  constexpr int BBYTES = 64 * BK * 2;
  constexpr int ISS = (AF32 ? 4 : 2) + 2;   // staging issues per wave per tile
  __shared__ __align__(16) char lds[3][ABYTES + BBYTES];

  const int tid = threadIdx.x;
  const int wid = tid >> 6;
  const int lane = tid & 63;
  const int wr = wid >> 1, wc = wid & 1;

  // XCD-aware bijective swizzle (gridDim.x % 8 == 0 for all our grids)
  const int nwg = gridDim.x;
  const int bid = (int)blockIdx.x;
  const int swz = (bid & 7) * (nwg >> 3) + (bid >> 3);
  const int nbn = N / 64;
  const int brow = (swz / nbn) * 64;
  const int bcol = (swz % nbn) * 64;

  f32x4 zero = {0.f, 0.f, 0.f, 0.f};
  f32x4 acc[2][2];
#pragma unroll
  for (int m = 0; m < 2; ++m)
#pragma unroll
    for (int n = 0; n < 2; ++n) acc[m][n] = zero;

  // ---- staging geometry ----
  // bf16 tile: issue = 8 rows x 128B; XOR swizzle on 16B chunks: phys c holds
  // logical c^(r&7); source col pre-swizzled.
  const int lr = lane >> 3;
  const int swzc = ((lane & 7) ^ lr) * 8;
  // f32 A tile: issue = 4 rows x 256B; XOR swizzle on 32B chunks (8 f32).
  const int a_r = lane >> 4;          // row within 4-row issue
  const int a_u = lane & 15;          // 16B unit within 256B row
  const int a_pc = a_u >> 1, a_h = a_u & 1;
  const int cole = (a_pc ^ a_r) * 8 + a_h * 4;        // even issues: key = a_r
  const int colo = (a_pc ^ (a_r + 4)) * 8 + a_h * 4;  // odd issues: key = a_r+4

  const float* Agf = (const float*)Av + (size_t)(brow + wid * 16 + a_r) * lda + k0;
  const unsigned short* Agh =
      (const unsigned short*)Av + (size_t)(brow + wid * 16 + lr) * lda + swzc + k0;
  const unsigned short* Bgh = Bt + (size_t)(bcol + wid * 16 + lr) * lda + swzc + k0;

  const int frow = lane & 15;
  const int fhi = lane >> 4;

  const int nsteps = kchunk / BK;

  auto stage = [&](int b, int t) {
    const int kofs = t * BK;
    char* dstA = lds[b] + wid * (AF32 ? 4096 : 2048);
    if constexpr (AF32) {
#pragma unroll
      for (int i = 0; i < 4; ++i)
        gload_lds16(Agf + kofs + (size_t)i * 4 * lda + ((i & 1) ? colo : cole),
                    dstA + i * 1024);
    } else {
#pragma unroll
      for (int i = 0; i < 2; ++i)
        gload_lds16(Agh + kofs + (size_t)i * 8 * lda, dstA + i * 1024);
    }
    char* dstB = lds[b] + ABYTES + wid * 2048;
#pragma unroll
    for (int i = 0; i < 2; ++i)
      gload_lds16(Bgh + kofs + (size_t)i * 8 * lda, dstB + i * 1024);
  };

  auto compute = [&](int b) {
    const char* base = lds[b];
    const unsigned short* Bs = (const unsigned short*)(base + ABYTES);
#pragma unroll
    for (int ks = 0; ks < 2; ++ks) {
      bf16x8 af[2], bg[2];
#pragma unroll
      for (int m = 0; m < 2; ++m) {
        int row = wr * 32 + m * 16 + frow;
        int pc = (ks * 4 + fhi) ^ (row & 7);
        if constexpr (AF32) {
          const float* ap = (const float*)base + row * 64 + pc * 8;
          float4 lo = *(const float4*)ap, hi = *(const float4*)(ap + 4);
          bf16x8 tv;
          tv[0] = (__bf16)lo.x; tv[1] = (__bf16)lo.y;
          tv[2] = (__bf16)lo.z; tv[3] = (__bf16)lo.w;
          tv[4] = (__bf16)hi.x; tv[5] = (__bf16)hi.y;
          tv[6] = (__bf16)hi.z; tv[7] = (__bf16)hi.w;
          af[m] = tv;
        } else {
          af[m] = *(const bf16x8*)((const unsigned short*)base + row * 64 + pc * 8);
        }
      }
#pragma unroll
      for (int n = 0; n < 2; ++n) {
        int row = wc * 32 + n * 16 + frow;
        int pc = (ks * 4 + fhi) ^ (row & 7);
        bg[n] = *(const bf16x8*)(Bs + row * 64 + pc * 8);
      }
#pragma unroll
      for (int m = 0; m < 2; ++m)
#pragma unroll
        for (int n = 0; n < 2; ++n)
          acc[m][n] = __builtin_amdgcn_mfma_f32_16x16x32_bf16(af[m], bg[n],
                                                              acc[m][n], 0, 0, 0);
    }
  };

  // prologue: tiles 0,1,2 in flight (nsteps >= 3 for all our shapes)
  stage(0, 0);
  stage(1, 1);
  stage(2, 2);

  int cur = 0;
  for (int t = 0; t + 2 < nsteps; ++t) {
    waitvm<2 * ISS>();            // oldest stage (tile t) landed
    barrier_fence();              // ...for ALL waves
    compute(cur);
    asm volatile("s_waitcnt lgkmcnt(0)" ::: "memory");  // my reads of cur done
    barrier_fence();              // all waves done reading cur
    if (t + 3 < nsteps) stage(cur, t + 3);
    cur = (cur == 2) ? 0 : cur + 1;
  }
  // t = nsteps-2: at most stages {nsteps-2, nsteps-1} outstanding
  waitvm<ISS>();
  barrier_fence();
  compute(cur);
  cur = (cur == 2) ? 0 : cur + 1;
  // t = nsteps-1
  waitvm<0>();
  barrier_fence();
  compute(cur);

  // ---- epilogue: D col = lane&15, row = (lane>>4)*4 + j ----
#pragma unroll
  for (int m = 0; m < 2; ++m) {
    int gr0 = brow + wr * 32 + m * 16 + fhi * 4;
#pragma unroll
    for (int n = 0; n < 2; ++n) {
      int gc = bcol + wc * 32 + n * 16 + frow;
#pragma unroll
      for (int j = 0; j < 4; ++j) {
        size_t idx = (size_t)(gr0 + j) * N + gc;
        float v = acc[m][n][j];
        if constexpr (EPI == 2) {
          v += e0[gc];
          outf[idx] = v > 0.f ? v : 0.f;
        } else {
          outf[idx] = v;
        }
      }
    }
  }
}

// ---- merged split-K partial GEMMs: y<2 -> context@W, y>=2 -> inputs@U ----
__global__ __launch_bounds__(256) void gemm01_kernel(
    const float* __restrict__ ctx, const unsigned short* __restrict__ Wt,
    const float* __restrict__ inp, const unsigned short* __restrict__ Ut,
    float* __restrict__ p0, float* __restrict__ p1) {
  const int y = blockIdx.y;
  const float* A;
  const unsigned short* Bt;
  int lda, kchunk, k0;
  float* outp;
  if (y < 2) {
    A = ctx; Bt = Wt; lda = 1024; kchunk = 512; k0 = y * 512;
    outp = p0 + (size_t)y * 2048 * 512;
  } else {
    A = inp; Bt = Ut; lda = 4096; kchunk = 1024; k0 = (y - 2) * 1024;
    outp = p1 + (size_t)(y - 2) * 2048 * 512;
  }
  gemm_core_pipe<3, true>(A, Bt, 512, lda, kchunk, k0, nullptr, outp);
}

// ---- final GEMM: out = relu(xus @ V^T + bias), all-bf16 ----
__global__ __launch_bounds__(256) void gemm2_kernel(
    const unsigned short* __restrict__ xus, const unsigned short* __restrict__ Vb,
    const float* __restrict__ bias, float* __restrict__ out) {
  gemm_core_pipe<2, false>(xus, Vb, 4096, 512, 512, 0, bias, out);
}

// ---- fused split-K reduce: xus = bf16((sum p1) * (S + sum p0)) ----
__global__ void reduce_mul_kernel(const float* __restrict__ p1,  // [4][MN]
                                  const float* __restrict__ p0,  // [2][MN]
                                  const float* __restrict__ Svec,  // [512]
                                  unsigned short* __restrict__ xus, int MN) {
  int i = blockIdx.x * blockDim.x + threadIdx.x;
  size_t base = (size_t)i * 4;
  if (base >= (size_t)MN) return;
  float4 a = *reinterpret_cast<const float4*>(p1 + base);
  float4 b = *reinterpret_cast<const float4*>(p1 + (size_t)MN + base);
  float4 c = *reinterpret_cast<const float4*>(p1 + 2 * (size_t)MN + base);
  float4 d = *reinterpret_cast<const float4*>(p1 + 3 * (size_t)MN + base);
  float4 s0 = *reinterpret_cast<const float4*>(p0 + base);
  float4 s1 = *reinterpret_cast<const float4*>(p0 + (size_t)MN + base);
  float4 sv = *reinterpret_cast<const float4*>(Svec + (base & 511));
  float4 xu, s;
  xu.x = (a.x + b.x) + (c.x + d.x);  s.x = s0.x + s1.x + sv.x;
  xu.y = (a.y + b.y) + (c.y + d.y);  s.y = s0.y + s1.y + sv.y;
  xu.z = (a.z + b.z) + (c.z + d.z);  s.z = s0.z + s1.z + sv.z;
  xu.w = (a.w + b.w) + (c.w + d.w);  s.w = s0.w + s1.w + sv.w;
  ushort4v o;
  o[0] = f2bf(xu.x * s.x);
  o[1] = f2bf(xu.y * s.y);
  o[2] = f2bf(xu.z * s.z);
  o[3] = f2bf(xu.w * s.w);
  *reinterpret_cast<ushort4v*>(xus + base) = o;
}

extern "C" void kernel_launch(void* const* d_in, const int* in_sizes, int n_in,
                              void* d_out, int out_size, void* d_ws, size_t ws_size,
                              hipStream_t stream) {
  constexpr int Bm = 2048, Nn = 4096, Cc = 1024, UU = 4096, RR = 512;
  const float* inputs  = (const float*)d_in[0];
  const float* context = (const float*)d_in[1];
  const float* U       = (const float*)d_in[2];
  const float* S       = (const float*)d_in[3];
  const float* V       = (const float*)d_in[4];
  const float* W       = (const float*)d_in[5];
  const float* bias    = (const float*)d_in[6];
  float* out = (float*)d_out;

  char* p = (char*)d_ws;
  unsigned short* Ut  = (unsigned short*)p; p += (size_t)RR * Nn * 2;      //  4 MB
  unsigned short* Wt  = (unsigned short*)p; p += (size_t)RR * Cc * 2;      //  1 MB
  unsigned short* Vb  = (unsigned short*)p; p += (size_t)UU * RR * 2;      //  4 MB
  float*          p0  = (float*)p;          p += (size_t)2 * Bm * RR * 4;  //  8 MB
  float*          p1  = (float*)p;          p += (size_t)4 * Bm * RR * 4;  // 16 MB
  unsigned short* xus = (unsigned short*)p; p += (size_t)Bm * RR * 2;      //  2 MB

  // 1) prep: U^T, W^T, V -> bf16 in one launch
  prep_kernel<<<3584, 256, 0, stream>>>(U, Ut, W, Wt, V, Vb);

  // 2) merged split-K partials: p0[2] = context@W chunks, p1[4] = inputs@U chunks
  gemm01_kernel<<<dim3((Bm / 64) * (RR / 64), 6), 256, 0, stream>>>(
      context, Wt, inputs, Ut, p0, p1);

  // 3) xus = bf16((sum p1) * (S + sum p0))
  reduce_mul_kernel<<<Bm * RR / 4 / 256, 256, 0, stream>>>(p1, p0, S, xus, Bm * RR);

  // 4) out = relu(xus @ V^T + bias)   (M=2048, N=4096, K=512, 64x64 tiles)
  gemm2_kernel<<<dim3((Bm / 64) * (UU / 64), 1), 256, 0, stream>>>(xus, Vb, bias, out);
}

// Round 6
// 60.905 us; speedup vs baseline: 1.7468x; 1.7468x over previous
//
#include <hip/hip_runtime.h>
#include <hip/hip_bf16.h>

typedef __attribute__((ext_vector_type(8))) __bf16 bf16x8;
typedef __attribute__((ext_vector_type(4))) float f32x4;
typedef __attribute__((ext_vector_type(8))) unsigned short ushort8;
typedef __attribute__((ext_vector_type(4))) unsigned short ushort4v;

__device__ __forceinline__ unsigned short f2bf(float f) {
  unsigned u = __builtin_bit_cast(unsigned, f);
  u += 0x7FFFu + ((u >> 16) & 1u);   // round-to-nearest-even
  return (unsigned short)(u >> 16);
}

__device__ __forceinline__ void gload_lds16(const void* g, void* l) {
  __builtin_amdgcn_global_load_lds(
      (const __attribute__((address_space(1))) void*)g,
      (__attribute__((address_space(3))) void*)l, 16, 0, 0);
}

// ---- prep: all operand conversions in ONE launch ----
// [0,2048)    : U[4096][512] -> Ut[512][4096] bf16 (transpose)
// [2048,2560) : W[1024][512] -> Wt[512][1024] bf16 (transpose)
// [2560,3584) : V   (2M f32) -> Vb bf16
// [3584,7680) : inputs (8M)  -> inb bf16
// [7680,8704) : context (2M) -> ctxb bf16
__global__ __launch_bounds__(256) void prep_kernel(
    const float* __restrict__ U, unsigned short* __restrict__ Ut,
    const float* __restrict__ W, unsigned short* __restrict__ Wt,
    const float* __restrict__ V, unsigned short* __restrict__ Vb,
    const float* __restrict__ inp, unsigned short* __restrict__ inb,
    const float* __restrict__ ctx, unsigned short* __restrict__ ctxb) {
  __shared__ float tile[32][33];
  const int b = blockIdx.x;
  const int tid = threadIdx.x;
  if (b < 2560) {
    const float* src;
    unsigned short* dst;
    int rows, cols, bx, by;
    if (b < 2048) {
      src = U; dst = Ut; rows = 4096; cols = 512;
      bx = (b & 15) * 32; by = (b >> 4) * 32;
    } else {
      int bb = b - 2048;
      src = W; dst = Wt; rows = 1024; cols = 512;
      bx = (bb & 15) * 32; by = (bb >> 4) * 32;
    }
    const int tx = tid & 31, ty = tid >> 5;
    for (int i = ty; i < 32; i += 8)
      tile[i][tx] = src[(size_t)(by + i) * cols + bx + tx];
    __syncthreads();
    for (int i = ty; i < 32; i += 8)
      dst[(size_t)(bx + i) * rows + by + tx] = f2bf(tile[tx][i]);
  } else {
    const float* src;
    unsigned short* dst;
    size_t i;
    if (b < 3584)      { src = V;   dst = Vb;   i = (size_t)(b - 2560) * 256 + tid; }
    else if (b < 7680) { src = inp; dst = inb;  i = (size_t)(b - 3584) * 256 + tid; }
    else               { src = ctx; dst = ctxb; i = (size_t)(b - 7680) * 256 + tid; }
    const float4* s4 = reinterpret_cast<const float4*>(src) + 2 * i;
    float4 a = s4[0], c = s4[1];
    ushort8 o;
    o[0] = f2bf(a.x); o[1] = f2bf(a.y); o[2] = f2bf(a.z); o[3] = f2bf(a.w);
    o[4] = f2bf(c.x); o[5] = f2bf(c.y); o[6] = f2bf(c.z); o[7] = f2bf(c.w);
    *(reinterpret_cast<ushort8*>(dst) + i) = o;
  }
}

// ------------- bf16 GEMM core: 64x128 tile (FM=2, FN=4) -------------
// C[64,128] = A[64,K] * Bt[128,K]^T, both operands bf16, staged via
// global_load_lds (fire-and-forget), 2-phase double-buffered pipeline,
// one barrier per K-step.  Measured-conflict-free XOR chunk swizzle.
// EPI 2: outf[idx] = relu(acc + e0[col]); EPI 3: outf[idx] = acc (partial).
template <int EPI>
__device__ __forceinline__ void gemm_core(
    const unsigned short* __restrict__ A, const unsigned short* __restrict__ Bt,
    int N, int lda, int kchunk, int k0, const float* __restrict__ e0,
    float* __restrict__ outf, int nwg, int bid) {
  constexpr int FM = 2, FN = 4;
  constexpr int BM = 32 * FM, BN = 32 * FN, BK = 64;
  constexpr int AI = BM / 32, BI = BN / 32;  // 1KB staging issues per wave
  __shared__ unsigned short lds[2][(BM + BN) * BK];

  const int tid = threadIdx.x;
  const int wid = tid >> 6;
  const int lane = tid & 63;
  const int wr = wid >> 1, wc = wid & 1;

  // XCD-aware bijective swizzle (nwg % 8 == 0 for all our segments)
  const int swz = (bid & 7) * (nwg >> 3) + (bid >> 3);
  const int nbn = N / BN;
  const int brow = (swz / nbn) * BM;
  const int bcol = (swz % nbn) * BN;

  f32x4 zero = {0.f, 0.f, 0.f, 0.f};
  f32x4 acc[FM][FN];
#pragma unroll
  for (int m = 0; m < FM; ++m)
#pragma unroll
    for (int n = 0; n < FN; ++n) acc[m][n] = zero;

  // staging: each issue = 8 rows x 64 bf16 = 1KB, linear LDS.
  // XOR swizzle: physical 16B chunk c at row r holds logical chunk c^(r&7);
  // source col pre-swizzled, read side applies ^(row&7).
  const int lr = lane >> 3;
  const int swzc = ((lane & 7) ^ lr) * 8;
  const unsigned short* Agh = A + (size_t)(brow + wid * (BM / 4) + lr) * lda + swzc + k0;
  const unsigned short* Bgh = Bt + (size_t)(bcol + wid * (BN / 4) + lr) * lda + swzc + k0;

  const int frow = lane & 15;
  const int fhi = lane >> 4;

  const int nsteps = kchunk / BK;

  auto stage = [&](int b, int kofs) {
    unsigned short* AsW = lds[b] + wid * (BM / 4) * 64;
#pragma unroll
    for (int i = 0; i < AI; ++i)
      gload_lds16(Agh + kofs + (size_t)i * 8 * lda, AsW + i * 512);
    unsigned short* BsW = lds[b] + BM * BK + wid * (BN / 4) * 64;
#pragma unroll
    for (int i = 0; i < BI; ++i)
      gload_lds16(Bgh + kofs + (size_t)i * 8 * lda, BsW + i * 512);
  };

  stage(0, 0);
  __syncthreads();  // implicit vmcnt(0) drain

  int cur = 0;
  for (int t = 0; t < nsteps; ++t) {
    if (t + 1 < nsteps) stage(cur ^ 1, (t + 1) * BK);  // in flight during MFMA
    const unsigned short* As = lds[cur];
    const unsigned short* Bs = lds[cur] + BM * BK;
#pragma unroll
    for (int ks = 0; ks < 2; ++ks) {
      bf16x8 af[FM], bg[FN];
#pragma unroll
      for (int m = 0; m < FM; ++m) {
        int row = wr * FM * 16 + m * 16 + frow;
        int pc = (ks * 4 + fhi) ^ (row & 7);
        af[m] = *reinterpret_cast<const bf16x8*>(As + row * 64 + pc * 8);
      }
#pragma unroll
      for (int n = 0; n < FN; ++n) {
        int row = wc * FN * 16 + n * 16 + frow;
        int pc = (ks * 4 + fhi) ^ (row & 7);
        bg[n] = *reinterpret_cast<const bf16x8*>(Bs + row * 64 + pc * 8);
      }
#pragma unroll
      for (int m = 0; m < FM; ++m)
#pragma unroll
        for (int n = 0; n < FN; ++n)
          acc[m][n] = __builtin_amdgcn_mfma_f32_16x16x32_bf16(af[m], bg[n],
                                                              acc[m][n], 0, 0, 0);
    }
    __syncthreads();  // drains vmcnt(0): next buffer landed; cur readers done
    cur ^= 1;
  }

  // epilogue: D col = lane&15, row = (lane>>4)*4 + j
#pragma unroll
  for (int m = 0; m < FM; ++m) {
    int gr0 = brow + wr * FM * 16 + m * 16 + fhi * 4;
#pragma unroll
    for (int n = 0; n < FN; ++n) {
      int gc = bcol + wc * FN * 16 + n * 16 + frow;
#pragma unroll
      for (int j = 0; j < 4; ++j) {
        size_t idx = (size_t)(gr0 + j) * N + gc;
        float v = acc[m][n][j];
        if constexpr (EPI == 2) {
          v += e0[gc];
          outf[idx] = v > 0.f ? v : 0.f;
        } else {
          outf[idx] = v;
        }
      }
    }
  }
}

// ---- merged split-K partial GEMMs, all-bf16 ----
// blocks [0,512)  : inputs@U  (lda 4096, kchunk 1024, split 4) -> p1
// blocks [512,768): context@W (lda 1024, kchunk  512, split 2) -> p0
__global__ __launch_bounds__(256) void gemm01_kernel(
    const unsigned short* __restrict__ inb, const unsigned short* __restrict__ Ut,
    const unsigned short* __restrict__ ctxb, const unsigned short* __restrict__ Wt,
    float* __restrict__ p0, float* __restrict__ p1) {
  const int bid = (int)blockIdx.x;
  constexpr size_t MN = (size_t)2048 * 512;
  if (bid < 512) {
    const int split = bid >> 7;          // 4 splits x 128 positions
    gemm_core<3>(inb, Ut, 512, 4096, 1024, split * 1024, nullptr,
                 p1 + split * MN, 128, bid & 127);
  } else {
    const int sb = bid - 512;
    const int split = sb >> 7;           // 2 splits x 128 positions
    gemm_core<3>(ctxb, Wt, 512, 1024, 512, split * 512, nullptr,
                 p0 + split * MN, 128, sb & 127);
  }
}

// ---- final GEMM: out = relu(xus @ V^T + bias) ----
__global__ __launch_bounds__(256) void gemm2_kernel(
    const unsigned short* __restrict__ xus, const unsigned short* __restrict__ Vb,
    const float* __restrict__ bias, float* __restrict__ out) {
  gemm_core<2>(xus, Vb, 4096, 512, 512, 0, bias, out, 1024, (int)blockIdx.x);
}

// ---- fused split-K reduce: xus = bf16((sum p1) * (S + sum p0)) ----
__global__ void reduce_mul_kernel(const float* __restrict__ p1,  // [4][MN]
                                  const float* __restrict__ p0,  // [2][MN]
                                  const float* __restrict__ Svec,  // [512]
                                  unsigned short* __restrict__ xus, int MN) {
  int i = blockIdx.x * blockDim.x + threadIdx.x;
  size_t base = (size_t)i * 4;
  if (base >= (size_t)MN) return;
  float4 a = *reinterpret_cast<const float4*>(p1 + base);
  float4 b = *reinterpret_cast<const float4*>(p1 + (size_t)MN + base);
  float4 c = *reinterpret_cast<const float4*>(p1 + 2 * (size_t)MN + base);
  float4 d = *reinterpret_cast<const float4*>(p1 + 3 * (size_t)MN + base);
  float4 s0 = *reinterpret_cast<const float4*>(p0 + base);
  float4 s1 = *reinterpret_cast<const float4*>(p0 + (size_t)MN + base);
  float4 sv = *reinterpret_cast<const float4*>(Svec + (base & 511));
  float4 xu, s;
  xu.x = (a.x + b.x) + (c.x + d.x);  s.x = s0.x + s1.x + sv.x;
  xu.y = (a.y + b.y) + (c.y + d.y);  s.y = s0.y + s1.y + sv.y;
  xu.z = (a.z + b.z) + (c.z + d.z);  s.z = s0.z + s1.z + sv.z;
  xu.w = (a.w + b.w) + (c.w + d.w);  s.w = s0.w + s1.w + sv.w;
  ushort4v o;
  o[0] = f2bf(xu.x * s.x);
  o[1] = f2bf(xu.y * s.y);
  o[2] = f2bf(xu.z * s.z);
  o[3] = f2bf(xu.w * s.w);
  *reinterpret_cast<ushort4v*>(xus + base) = o;
}

extern "C" void kernel_launch(void* const* d_in, const int* in_sizes, int n_in,
                              void* d_out, int out_size, void* d_ws, size_t ws_size,
                              hipStream_t stream) {
  constexpr int Bm = 2048, Nn = 4096, Cc = 1024, UU = 4096, RR = 512;
  const float* inputs  = (const float*)d_in[0];
  const float* context = (const float*)d_in[1];
  const float* U       = (const float*)d_in[2];
  const float* S       = (const float*)d_in[3];
  const float* V       = (const float*)d_in[4];
  const float* W       = (const float*)d_in[5];
  const float* bias    = (const float*)d_in[6];
  float* out = (float*)d_out;

  char* p = (char*)d_ws;
  unsigned short* Ut   = (unsigned short*)p; p += (size_t)RR * Nn * 2;      //  4 MB
  unsigned short* Wt   = (unsigned short*)p; p += (size_t)RR * Cc * 2;      //  1 MB
  unsigned short* Vb   = (unsigned short*)p; p += (size_t)UU * RR * 2;      //  4 MB
  unsigned short* inb  = (unsigned short*)p; p += (size_t)Bm * Nn * 2;      // 16 MB
  unsigned short* ctxb = (unsigned short*)p; p += (size_t)Bm * Cc * 2;      //  4 MB
  float*          p0   = (float*)p;          p += (size_t)2 * Bm * RR * 4;  //  8 MB
  float*          p1   = (float*)p;          p += (size_t)4 * Bm * RR * 4;  // 16 MB
  unsigned short* xus  = (unsigned short*)p; p += (size_t)Bm * RR * 2;      //  2 MB

  // 1) prep: all conversions (U^T, W^T, V, inputs, context -> bf16)
  prep_kernel<<<8704, 256, 0, stream>>>(U, Ut, W, Wt, V, Vb, inputs, inb,
                                        context, ctxb);

  // 2) merged split-K partials: p1[4] = inputs@U chunks, p0[2] = context@W chunks
  gemm01_kernel<<<768, 256, 0, stream>>>(inb, Ut, ctxb, Wt, p0, p1);

  // 3) xus = bf16((sum p1) * (S + sum p0))
  reduce_mul_kernel<<<Bm * RR / 4 / 256, 256, 0, stream>>>(p1, p0, S, xus, Bm * RR);

  // 4) out = relu(xus @ V^T + bias)   (M=2048, N=4096, K=512, 64x128 tiles)
  gemm2_kernel<<<1024, 256, 0, stream>>>(xus, Vb, bias, out);
}

// Round 8
// 59.390 us; speedup vs baseline: 1.7914x; 1.0255x over previous
//
#include <hip/hip_runtime.h>
#include <hip/hip_bf16.h>

typedef __attribute__((ext_vector_type(8))) __bf16 bf16x8;
typedef __attribute__((ext_vector_type(4))) float f32x4;
typedef __attribute__((ext_vector_type(8))) unsigned short ushort8;
typedef __attribute__((ext_vector_type(4))) unsigned short ushort4v;

__device__ __forceinline__ unsigned short f2bf(float f) {
  unsigned u = __builtin_bit_cast(unsigned, f);
  u += 0x7FFFu + ((u >> 16) & 1u);   // round-to-nearest-even
  return (unsigned short)(u >> 16);
}

__device__ __forceinline__ void gload_lds16(const void* g, void* l) {
  __builtin_amdgcn_global_load_lds(
      (const __attribute__((address_space(1))) void*)g,
      (__attribute__((address_space(3))) void*)l, 16, 0, 0);
}

__device__ __forceinline__ void barrier_fence() {
  __builtin_amdgcn_s_barrier();
  asm volatile("" ::: "memory");
}

// ---- prep: all operand conversions in ONE launch ----
// [0,2048)    : U[4096][512] -> Ut[512][4096] bf16 (transpose)
// [2048,2560) : W[1024][512] -> Wt[512][1024] bf16 (transpose)
// [2560,3584) : V   (2M f32) -> Vb bf16
// [3584,7680) : inputs (8M)  -> inb bf16
// [7680,8704) : context (2M) -> ctxb bf16
__global__ __launch_bounds__(256) void prep_kernel(
    const float* __restrict__ U, unsigned short* __restrict__ Ut,
    const float* __restrict__ W, unsigned short* __restrict__ Wt,
    const float* __restrict__ V, unsigned short* __restrict__ Vb,
    const float* __restrict__ inp, unsigned short* __restrict__ inb,
    const float* __restrict__ ctx, unsigned short* __restrict__ ctxb) {
  __shared__ float tile[32][33];
  const int b = blockIdx.x;
  const int tid = threadIdx.x;
  if (b < 2560) {
    const float* src;
    unsigned short* dst;
    int rows, cols, bx, by;
    if (b < 2048) {
      src = U; dst = Ut; rows = 4096; cols = 512;
      bx = (b & 15) * 32; by = (b >> 4) * 32;
    } else {
      int bb = b - 2048;
      src = W; dst = Wt; rows = 1024; cols = 512;
      bx = (bb & 15) * 32; by = (bb >> 4) * 32;
    }
    const int tx = tid & 31, ty = tid >> 5;
    for (int i = ty; i < 32; i += 8)
      tile[i][tx] = src[(size_t)(by + i) * cols + bx + tx];
    __syncthreads();
    for (int i = ty; i < 32; i += 8)
      dst[(size_t)(bx + i) * rows + by + tx] = f2bf(tile[tx][i]);
  } else {
    const float* src;
    unsigned short* dst;
    size_t i;
    if (b < 3584)      { src = V;   dst = Vb;   i = (size_t)(b - 2560) * 256 + tid; }
    else if (b < 7680) { src = inp; dst = inb;  i = (size_t)(b - 3584) * 256 + tid; }
    else               { src = ctx; dst = ctxb; i = (size_t)(b - 7680) * 256 + tid; }
    const float4* s4 = reinterpret_cast<const float4*>(src) + 2 * i;
    float4 a = s4[0], c = s4[1];
    ushort8 o;
    o[0] = f2bf(a.x); o[1] = f2bf(a.y); o[2] = f2bf(a.z); o[3] = f2bf(a.w);
    o[4] = f2bf(c.x); o[5] = f2bf(c.y); o[6] = f2bf(c.z); o[7] = f2bf(c.w);
    *(reinterpret_cast<ushort8*>(dst) + i) = o;
  }
}

// ------------- bf16 GEMM core: 64x128 tile (FM=2, FN=4) -------------
// C[64,128] = A[64,K] * Bt[128,K]^T, both bf16 via global_load_lds.
// T4 counted-vmcnt 2-buffer pipeline: per step
//   wait vmcnt(6) -> barrier -> compute(cur) -> lgkmcnt(0) -> barrier
//   -> stage(cur, t+2)
// vmcnt never drains to 0 in the main loop; each stage = exactly ISS=6
// loads per wave, so vmcnt(6) == "tile t landed (my portion)".
// EPI 2: outf[idx] = relu(acc + e0[col]); EPI 3: outf[idx] = acc (partial).
template <int EPI>
__device__ __forceinline__ void gemm_core(
    const unsigned short* __restrict__ A, const unsigned short* __restrict__ Bt,
    int N, int lda, int kchunk, int k0, const float* __restrict__ e0,
    float* __restrict__ outf, int nwg, int bid) {
  constexpr int FM = 2, FN = 4;
  constexpr int BM = 32 * FM, BN = 32 * FN, BK = 64;
  constexpr int AI = BM / 32, BI = BN / 32;  // 1KB staging issues per wave
  __shared__ unsigned short lds[2][(BM + BN) * BK];

  const int tid = threadIdx.x;
  const int wid = tid >> 6;
  const int lane = tid & 63;
  const int wr = wid >> 1, wc = wid & 1;

  // XCD-aware bijective swizzle (nwg % 8 == 0 for all our segments)
  const int swz = (bid & 7) * (nwg >> 3) + (bid >> 3);
  const int nbn = N / BN;
  const int brow = (swz / nbn) * BM;
  const int bcol = (swz % nbn) * BN;

  f32x4 zero = {0.f, 0.f, 0.f, 0.f};
  f32x4 acc[FM][FN];
#pragma unroll
  for (int m = 0; m < FM; ++m)
#pragma unroll
    for (int n = 0; n < FN; ++n) acc[m][n] = zero;

  // staging: each issue = 8 rows x 64 bf16 = 1KB, linear LDS.
  // XOR swizzle: physical 16B chunk c at row r holds logical chunk c^(r&7);
  // source col pre-swizzled, read side applies ^(row&7).
  const int lr = lane >> 3;
  const int swzc = ((lane & 7) ^ lr) * 8;
  const unsigned short* Agh = A + (size_t)(brow + wid * (BM / 4) + lr) * lda + swzc + k0;
  const unsigned short* Bgh = Bt + (size_t)(bcol + wid * (BN / 4) + lr) * lda + swzc + k0;

  const int frow = lane & 15;
  const int fhi = lane >> 4;

  const int nsteps = kchunk / BK;   // >= 2 for all our shapes

  auto stage = [&](int b, int kofs) {   // kofs in ELEMENTS (t*BK)
    unsigned short* AsW = lds[b] + wid * (BM / 4) * 64;
#pragma unroll
    for (int i = 0; i < AI; ++i)
      gload_lds16(Agh + kofs + (size_t)i * 8 * lda, AsW + i * 512);
    unsigned short* BsW = lds[b] + BM * BK + wid * (BN / 4) * 64;
#pragma unroll
    for (int i = 0; i < BI; ++i)
      gload_lds16(Bgh + kofs + (size_t)i * 8 * lda, BsW + i * 512);
  };

  auto compute = [&](int cur) {
    const unsigned short* As = lds[cur];
    const unsigned short* Bs = lds[cur] + BM * BK;
#pragma unroll
    for (int ks = 0; ks < 2; ++ks) {
      bf16x8 af[FM], bg[FN];
#pragma unroll
      for (int m = 0; m < FM; ++m) {
        int row = wr * FM * 16 + m * 16 + frow;
        int pc = (ks * 4 + fhi) ^ (row & 7);
        af[m] = *reinterpret_cast<const bf16x8*>(As + row * 64 + pc * 8);
      }
#pragma unroll
      for (int n = 0; n < FN; ++n) {
        int row = wc * FN * 16 + n * 16 + frow;
        int pc = (ks * 4 + fhi) ^ (row & 7);
        bg[n] = *reinterpret_cast<const bf16x8*>(Bs + row * 64 + pc * 8);
      }
#pragma unroll
      for (int m = 0; m < FM; ++m)
#pragma unroll
        for (int n = 0; n < FN; ++n)
          acc[m][n] = __builtin_amdgcn_mfma_f32_16x16x32_bf16(af[m], bg[n],
                                                              acc[m][n], 0, 0, 0);
    }
  };

  // prologue: tiles 0 and 1 in flight (kofs units: ELEMENTS)
  stage(0, 0);
  stage(1, BK);

  int cur = 0;
  for (int t = 0; t < nsteps; ++t) {
    if (t + 1 < nsteps)
      asm volatile("s_waitcnt vmcnt(6)" ::: "memory");  // tile t landed (mine)
    else
      asm volatile("s_waitcnt vmcnt(0)" ::: "memory");  // last tile
    barrier_fence();                                    // ...for all waves
    compute(cur);
    if (t + 1 < nsteps) {
      asm volatile("s_waitcnt lgkmcnt(0)" ::: "memory");  // my reads of cur done
      barrier_fence();                                    // all waves done with cur
      if (t + 2 < nsteps) stage(cur, (t + 2) * BK);       // refill freed buffer
    }
    cur ^= 1;
  }

  // epilogue: D col = lane&15, row = (lane>>4)*4 + j
#pragma unroll
  for (int m = 0; m < FM; ++m) {
    int gr0 = brow + wr * FM * 16 + m * 16 + fhi * 4;
#pragma unroll
    for (int n = 0; n < FN; ++n) {
      int gc = bcol + wc * FN * 16 + n * 16 + frow;
#pragma unroll
      for (int j = 0; j < 4; ++j) {
        size_t idx = (size_t)(gr0 + j) * N + gc;
        float v = acc[m][n][j];
        if constexpr (EPI == 2) {
          v += e0[gc];
          outf[idx] = v > 0.f ? v : 0.f;
        } else {
          outf[idx] = v;
        }
      }
    }
  }
}

// ---- merged split-K partial GEMMs, all-bf16 ----
// blocks [0,512)  : inputs@U  (lda 4096, kchunk 1024, split 4) -> p1
// blocks [512,768): context@W (lda 1024, kchunk  512, split 2) -> p0
__global__ __launch_bounds__(256) void gemm01_kernel(
    const unsigned short* __restrict__ inb, const unsigned short* __restrict__ Ut,
    const unsigned short* __restrict__ ctxb, const unsigned short* __restrict__ Wt,
    float* __restrict__ p0, float* __restrict__ p1) {
  const int bid = (int)blockIdx.x;
  constexpr size_t MN = (size_t)2048 * 512;
  if (bid < 512) {
    const int split = bid >> 7;          // 4 splits x 128 positions
    gemm_core<3>(inb, Ut, 512, 4096, 1024, split * 1024, nullptr,
                 p1 + split * MN, 128, bid & 127);
  } else {
    const int sb = bid - 512;
    const int split = sb >> 7;           // 2 splits x 128 positions
    gemm_core<3>(ctxb, Wt, 512, 1024, 512, split * 512, nullptr,
                 p0 + split * MN, 128, sb & 127);
  }
}

// ---- final GEMM: out = relu(xus @ V^T + bias) ----
__global__ __launch_bounds__(256) void gemm2_kernel(
    const unsigned short* __restrict__ xus, const unsigned short* __restrict__ Vb,
    const float* __restrict__ bias, float* __restrict__ out) {
  gemm_core<2>(xus, Vb, 4096, 512, 512, 0, bias, out, 1024, (int)blockIdx.x);
}

// ---- fused split-K reduce: xus = bf16((sum p1) * (S + sum p0)) ----
__global__ void reduce_mul_kernel(const float* __restrict__ p1,  // [4][MN]
                                  const float* __restrict__ p0,  // [2][MN]
                                  const float* __restrict__ Svec,  // [512]
                                  unsigned short* __restrict__ xus, int MN) {
  int i = blockIdx.x * blockDim.x + threadIdx.x;
  size_t base = (size_t)i * 4;
  if (base >= (size_t)MN) return;
  float4 a = *reinterpret_cast<const float4*>(p1 + base);
  float4 b = *reinterpret_cast<const float4*>(p1 + (size_t)MN + base);
  float4 c = *reinterpret_cast<const float4*>(p1 + 2 * (size_t)MN + base);
  float4 d = *reinterpret_cast<const float4*>(p1 + 3 * (size_t)MN + base);
  float4 s0 = *reinterpret_cast<const float4*>(p0 + base);
  float4 s1 = *reinterpret_cast<const float4*>(p0 + (size_t)MN + base);
  float4 sv = *reinterpret_cast<const float4*>(Svec + (base & 511));
  float4 xu, s;
  xu.x = (a.x + b.x) + (c.x + d.x);  s.x = s0.x + s1.x + sv.x;
  xu.y = (a.y + b.y) + (c.y + d.y);  s.y = s0.y + s1.y + sv.y;
  xu.z = (a.z + b.z) + (c.z + d.z);  s.z = s0.z + s1.z + sv.z;
  xu.w = (a.w + b.w) + (c.w + d.w);  s.w = s0.w + s1.w + sv.w;
  ushort4v o;
  o[0] = f2bf(xu.x * s.x);
  o[1] = f2bf(xu.y * s.y);
  o[2] = f2bf(xu.z * s.z);
  o[3] = f2bf(xu.w * s.w);
  *reinterpret_cast<ushort4v*>(xus + base) = o;
}

extern "C" void kernel_launch(void* const* d_in, const int* in_sizes, int n_in,
                              void* d_out, int out_size, void* d_ws, size_t ws_size,
                              hipStream_t stream) {
  constexpr int Bm = 2048, Nn = 4096, Cc = 1024, UU = 4096, RR = 512;
  const float* inputs  = (const float*)d_in[0];
  const float* context = (const float*)d_in[1];
  const float* U       = (const float*)d_in[2];
  const float* S       = (const float*)d_in[3];
  const float* V       = (const float*)d_in[4];
  const float* W       = (const float*)d_in[5];
  const float* bias    = (const float*)d_in[6];
  float* out = (float*)d_out;

  char* p = (char*)d_ws;
  unsigned short* Ut   = (unsigned short*)p; p += (size_t)RR * Nn * 2;      //  4 MB
  unsigned short* Wt   = (unsigned short*)p; p += (size_t)RR * Cc * 2;      //  1 MB
  unsigned short* Vb   = (unsigned short*)p; p += (size_t)UU * RR * 2;      //  4 MB
  unsigned short* inb  = (unsigned short*)p; p += (size_t)Bm * Nn * 2;      // 16 MB
  unsigned short* ctxb = (unsigned short*)p; p += (size_t)Bm * Cc * 2;      //  4 MB
  float*          p0   = (float*)p;          p += (size_t)2 * Bm * RR * 4;  //  8 MB
  float*          p1   = (float*)p;          p += (size_t)4 * Bm * RR * 4;  // 16 MB
  unsigned short* xus  = (unsigned short*)p; p += (size_t)Bm * RR * 2;      //  2 MB

  // 1) prep: all conversions (U^T, W^T, V, inputs, context -> bf16)
  prep_kernel<<<8704, 256, 0, stream>>>(U, Ut, W, Wt, V, Vb, inputs, inb,
                                        context, ctxb);

  // 2) merged split-K partials: p1[4] = inputs@U chunks, p0[2] = context@W chunks
  gemm01_kernel<<<768, 256, 0, stream>>>(inb, Ut, ctxb, Wt, p0, p1);

  // 3) xus = bf16((sum p1) * (S + sum p0))
  reduce_mul_kernel<<<Bm * RR / 4 / 256, 256, 0, stream>>>(p1, p0, S, xus, Bm * RR);

  // 4) out = relu(xus @ V^T + bias)   (M=2048, N=4096, K=512, 64x128 tiles)
  gemm2_kernel<<<1024, 256, 0, stream>>>(xus, Vb, bias, out);
}

// Round 9
// 58.247 us; speedup vs baseline: 1.8265x; 1.0196x over previous
//
#include <hip/hip_runtime.h>
#include <hip/hip_bf16.h>

typedef __attribute__((ext_vector_type(8))) __bf16 bf16x8;
typedef __attribute__((ext_vector_type(4))) float f32x4;
typedef __attribute__((ext_vector_type(8))) unsigned short ushort8;
typedef __attribute__((ext_vector_type(4))) unsigned short ushort4v;

__device__ __forceinline__ unsigned short f2bf(float f) {
  unsigned u = __builtin_bit_cast(unsigned, f);
  u += 0x7FFFu + ((u >> 16) & 1u);   // round-to-nearest-even
  return (unsigned short)(u >> 16);
}

__device__ __forceinline__ void gload_lds16(const void* g, void* l) {
  __builtin_amdgcn_global_load_lds(
      (const __attribute__((address_space(1))) void*)g,
      (__attribute__((address_space(3))) void*)l, 16, 0, 0);
}

__device__ __forceinline__ void barrier_fence() {
  __builtin_amdgcn_s_barrier();
  asm volatile("" ::: "memory");
}

template <int N>
__device__ __forceinline__ void waitvm() {
  if constexpr (N == 0)      asm volatile("s_waitcnt vmcnt(0)" ::: "memory");
  else if constexpr (N == 6) asm volatile("s_waitcnt vmcnt(6)" ::: "memory");
  else if constexpr (N == 8) asm volatile("s_waitcnt vmcnt(8)" ::: "memory");
}

// ---- prep: weight conversions only (A-side conversion fused into gemm01) ----
// [0,2048)    : U[4096][512] -> Ut[512][4096] bf16 (transpose)
// [2048,2560) : W[1024][512] -> Wt[512][1024] bf16 (transpose)
// [2560,3584) : V   (2M f32) -> Vb bf16
__global__ __launch_bounds__(256) void prep_kernel(
    const float* __restrict__ U, unsigned short* __restrict__ Ut,
    const float* __restrict__ W, unsigned short* __restrict__ Wt,
    const float* __restrict__ V, unsigned short* __restrict__ Vb) {
  __shared__ float tile[32][33];
  const int b = blockIdx.x;
  const int tid = threadIdx.x;
  if (b < 2560) {
    const float* src;
    unsigned short* dst;
    int rows, cols, bx, by;
    if (b < 2048) {
      src = U; dst = Ut; rows = 4096; cols = 512;
      bx = (b & 15) * 32; by = (b >> 4) * 32;
    } else {
      int bb = b - 2048;
      src = W; dst = Wt; rows = 1024; cols = 512;
      bx = (bb & 15) * 32; by = (bb >> 4) * 32;
    }
    const int tx = tid & 31, ty = tid >> 5;
    for (int i = ty; i < 32; i += 8)
      tile[i][tx] = src[(size_t)(by + i) * cols + bx + tx];
    __syncthreads();
    for (int i = ty; i < 32; i += 8)
      dst[(size_t)(bx + i) * rows + by + tx] = f2bf(tile[tx][i]);
  } else {
    const size_t i = (size_t)(b - 2560) * 256 + tid;  // 8 f32 per thread
    const float4* s4 = reinterpret_cast<const float4*>(V) + 2 * i;
    float4 a = s4[0], c = s4[1];
    ushort8 o;
    o[0] = f2bf(a.x); o[1] = f2bf(a.y); o[2] = f2bf(a.z); o[3] = f2bf(a.w);
    o[4] = f2bf(c.x); o[5] = f2bf(c.y); o[6] = f2bf(c.z); o[7] = f2bf(c.w);
    *(reinterpret_cast<ushort8*>(Vb) + i) = o;
  }
}

// ------------- GEMM core: 64x128 tile (FM=2, FN=4), BK=64 -------------
// C[64,128] = A[64,K] * Bt[128,K]^T.  B always bf16 via global_load_lds.
// AF32: A staged as RAW F32 via global_load_lds (16B-chunk XOR swizzle,
// key=row&7 -> same zero-conflict profile as the bf16 layout), converted
// to bf16 at fragment-read time.  !AF32: A bf16, classic layout.
// T4 counted-vmcnt 2-buffer pipeline: per step
//   wait vmcnt(ISS) -> barrier -> compute(cur) -> lgkmcnt(0) -> barrier
//   -> stage(cur, t+2).   vmcnt never drains to 0 in the main loop.
// EPI 2: outf[idx] = relu(acc + e0[col]); EPI 3: outf[idx] = acc (partial).
template <int EPI, bool AF32>
__device__ __forceinline__ void gemm_core(
    const void* __restrict__ Av, const unsigned short* __restrict__ Bt,
    int N, int lda, int kchunk, int k0, const float* __restrict__ e0,
    float* __restrict__ outf, int nwg, int bid) {
  constexpr int FM = 2, FN = 4;
  constexpr int BM = 32 * FM, BN = 32 * FN, BK = 64;
  constexpr int ABYTES = BM * BK * (AF32 ? 4 : 2);   // 16KB or 8KB
  constexpr int AI = AF32 ? 4 : 2;   // 1KB staging issues per wave (A)
  constexpr int BI = 4;              // 1KB staging issues per wave (B)
  constexpr int ISS = AI + BI;
  __shared__ __align__(16) char lds[2][ABYTES + BN * BK * 2];

  const int tid = threadIdx.x;
  const int wid = tid >> 6;
  const int lane = tid & 63;
  const int wr = wid >> 1, wc = wid & 1;

  // XCD-aware bijective swizzle (nwg % 8 == 0 for all our segments)
  const int swz = (bid & 7) * (nwg >> 3) + (bid >> 3);
  const int nbn = N / BN;
  const int brow = (swz / nbn) * BM;
  const int bcol = (swz % nbn) * BN;

  f32x4 zero = {0.f, 0.f, 0.f, 0.f};
  f32x4 acc[FM][FN];
#pragma unroll
  for (int m = 0; m < FM; ++m)
#pragma unroll
    for (int n = 0; n < FN; ++n) acc[m][n] = zero;

  // ---- staging geometry ----
  // bf16 (B, and A when !AF32): issue = 8 rows x 128B; phys 16B chunk c at
  // row r holds logical chunk c^(r&7); source col pre-swizzled.
  const int lr = lane >> 3;
  const int swzc = ((lane & 7) ^ lr) * 8;
  // f32 A: issue = 4 rows x 256B (16 chunks of 16B); phys chunk c at row r
  // holds logical chunk c^(r&7).  r&7 = 4*(issue&1) + (lane>>4).
  const int a4r = lane >> 4;            // row within 4-row issue
  const int a4c = lane & 15;            // phys 16B chunk
  const int colE = ((a4c ^ a4r) << 2);            // f32 col, even issues
  const int colO = ((a4c ^ (4 + a4r)) << 2);      // f32 col, odd issues

  const float* Agf =
      (const float*)Av + (size_t)(brow + wid * 16 + a4r) * lda + k0;
  const unsigned short* Agh =
      (const unsigned short*)Av + (size_t)(brow + wid * 16 + lr) * lda + swzc + k0;
  const unsigned short* Bgh = Bt + (size_t)(bcol + wid * 32 + lr) * lda + swzc + k0;

  const int frow = lane & 15;
  const int fhi = lane >> 4;

  const int nsteps = kchunk / BK;   // >= 3 for all our shapes

  auto stage = [&](int b, int kofs) {   // kofs in ELEMENTS (t*BK)
    char* dstA = lds[b] + wid * (AF32 ? 4096 : 2048);
    if constexpr (AF32) {
#pragma unroll
      for (int i = 0; i < 4; ++i)
        gload_lds16(Agf + kofs + (size_t)(4 * i) * lda + ((i & 1) ? colO : colE),
                    dstA + i * 1024);
    } else {
#pragma unroll
      for (int i = 0; i < 2; ++i)
        gload_lds16(Agh + kofs + (size_t)(8 * i) * lda, dstA + i * 1024);
    }
    char* dstB = lds[b] + ABYTES + wid * 4096;
#pragma unroll
    for (int i = 0; i < BI; ++i)
      gload_lds16(Bgh + kofs + (size_t)(8 * i) * lda, dstB + i * 1024);
  };

  auto compute = [&](int cur) {
    const char* base = lds[cur];
    const unsigned short* Bs = (const unsigned short*)(base + ABYTES);
#pragma unroll
    for (int ks = 0; ks < 2; ++ks) {
      bf16x8 af[FM], bg[FN];
#pragma unroll
      for (int m = 0; m < FM; ++m) {
        int row = wr * FM * 16 + m * 16 + frow;
        int j = ks * 4 + fhi;
        if constexpr (AF32) {
          const float* ap = (const float*)base + row * 64;
          int r7 = row & 7;
          float4 lo = *(const float4*)(ap + (((2 * j) ^ r7) << 2));
          float4 hi = *(const float4*)(ap + (((2 * j + 1) ^ r7) << 2));
          bf16x8 tv;
          tv[0] = (__bf16)lo.x; tv[1] = (__bf16)lo.y;
          tv[2] = (__bf16)lo.z; tv[3] = (__bf16)lo.w;
          tv[4] = (__bf16)hi.x; tv[5] = (__bf16)hi.y;
          tv[6] = (__bf16)hi.z; tv[7] = (__bf16)hi.w;
          af[m] = tv;
        } else {
          int pc = j ^ (row & 7);
          af[m] = *(const bf16x8*)((const unsigned short*)base + row * 64 + pc * 8);
        }
      }
#pragma unroll
      for (int n = 0; n < FN; ++n) {
        int row = wc * FN * 16 + n * 16 + frow;
        int pc = (ks * 4 + fhi) ^ (row & 7);
        bg[n] = *(const bf16x8*)(Bs + row * 64 + pc * 8);
      }
#pragma unroll
      for (int m = 0; m < FM; ++m)
#pragma unroll
        for (int n = 0; n < FN; ++n)
          acc[m][n] = __builtin_amdgcn_mfma_f32_16x16x32_bf16(af[m], bg[n],
                                                              acc[m][n], 0, 0, 0);
    }
  };

  // prologue: tiles 0 and 1 in flight
  stage(0, 0);
  stage(1, BK);

  int cur = 0;
  for (int t = 0; t < nsteps; ++t) {
    if (t + 1 < nsteps)
      waitvm<ISS>();   // tile t landed (my portion)
    else
      waitvm<0>();     // last tile
    barrier_fence();   // ...for all waves
    compute(cur);
    if (t + 1 < nsteps) {
      asm volatile("s_waitcnt lgkmcnt(0)" ::: "memory");  // my reads of cur done
      barrier_fence();                                    // all waves done with cur
      if (t + 2 < nsteps) stage(cur, (t + 2) * BK);       // refill freed buffer
    }
    cur ^= 1;
  }

  // epilogue: D col = lane&15, row = (lane>>4)*4 + j
#pragma unroll
  for (int m = 0; m < FM; ++m) {
    int gr0 = brow + wr * FM * 16 + m * 16 + fhi * 4;
#pragma unroll
    for (int n = 0; n < FN; ++n) {
      int gc = bcol + wc * FN * 16 + n * 16 + frow;
#pragma unroll
      for (int j = 0; j < 4; ++j) {
        size_t idx = (size_t)(gr0 + j) * N + gc;
        float v = acc[m][n][j];
        if constexpr (EPI == 2) {
          v += e0[gc];
          outf[idx] = v > 0.f ? v : 0.f;
        } else {
          outf[idx] = v;
        }
      }
    }
  }
}

// ---- merged split-K partial GEMMs, A = f32 direct (fused conversion) ----
// blocks [0,512)  : inputs@U  (lda 4096, kchunk 1024, split 4) -> p1
// blocks [512,768): context@W (lda 1024, kchunk  512, split 2) -> p0
__global__ __launch_bounds__(256) void gemm01_kernel(
    const float* __restrict__ inp, const unsigned short* __restrict__ Ut,
    const float* __restrict__ ctx, const unsigned short* __restrict__ Wt,
    float* __restrict__ p0, float* __restrict__ p1) {
  const int bid = (int)blockIdx.x;
  constexpr size_t MN = (size_t)2048 * 512;
  if (bid < 512) {
    const int split = bid >> 7;          // 4 splits x 128 positions
    gemm_core<3, true>(inp, Ut, 512, 4096, 1024, split * 1024, nullptr,
                       p1 + split * MN, 128, bid & 127);
  } else {
    const int sb = bid - 512;
    const int split = sb >> 7;           // 2 splits x 128 positions
    gemm_core<3, true>(ctx, Wt, 512, 1024, 512, split * 512, nullptr,
                       p0 + split * MN, 128, sb & 127);
  }
}

// ---- final GEMM: out = relu(xus @ V^T + bias), all-bf16 ----
__global__ __launch_bounds__(256) void gemm2_kernel(
    const unsigned short* __restrict__ xus, const unsigned short* __restrict__ Vb,
    const float* __restrict__ bias, float* __restrict__ out) {
  gemm_core<2, false>(xus, Vb, 4096, 512, 512, 0, bias, out, 1024,
                      (int)blockIdx.x);
}

// ---- fused split-K reduce: xus = bf16((sum p1) * (S + sum p0)) ----
__global__ void reduce_mul_kernel(const float* __restrict__ p1,  // [4][MN]
                                  const float* __restrict__ p0,  // [2][MN]
                                  const float* __restrict__ Svec,  // [512]
                                  unsigned short* __restrict__ xus, int MN) {
  int i = blockIdx.x * blockDim.x + threadIdx.x;
  size_t base = (size_t)i * 4;
  if (base >= (size_t)MN) return;
  float4 a = *reinterpret_cast<const float4*>(p1 + base);
  float4 b = *reinterpret_cast<const float4*>(p1 + (size_t)MN + base);
  float4 c = *reinterpret_cast<const float4*>(p1 + 2 * (size_t)MN + base);
  float4 d = *reinterpret_cast<const float4*>(p1 + 3 * (size_t)MN + base);
  float4 s0 = *reinterpret_cast<const float4*>(p0 + base);
  float4 s1 = *reinterpret_cast<const float4*>(p0 + (size_t)MN + base);
  float4 sv = *reinterpret_cast<const float4*>(Svec + (base & 511));
  float4 xu, s;
  xu.x = (a.x + b.x) + (c.x + d.x);  s.x = s0.x + s1.x + sv.x;
  xu.y = (a.y + b.y) + (c.y + d.y);  s.y = s0.y + s1.y + sv.y;
  xu.z = (a.z + b.z) + (c.z + d.z);  s.z = s0.z + s1.z + sv.z;
  xu.w = (a.w + b.w) + (c.w + d.w);  s.w = s0.w + s1.w + sv.w;
  ushort4v o;
  o[0] = f2bf(xu.x * s.x);
  o[1] = f2bf(xu.y * s.y);
  o[2] = f2bf(xu.z * s.z);
  o[3] = f2bf(xu.w * s.w);
  *reinterpret_cast<ushort4v*>(xus + base) = o;
}

extern "C" void kernel_launch(void* const* d_in, const int* in_sizes, int n_in,
                              void* d_out, int out_size, void* d_ws, size_t ws_size,
                              hipStream_t stream) {
  constexpr int Bm = 2048, Nn = 4096, Cc = 1024, UU = 4096, RR = 512;
  const float* inputs  = (const float*)d_in[0];
  const float* context = (const float*)d_in[1];
  const float* U       = (const float*)d_in[2];
  const float* S       = (const float*)d_in[3];
  const float* V       = (const float*)d_in[4];
  const float* W       = (const float*)d_in[5];
  const float* bias    = (const float*)d_in[6];
  float* out = (float*)d_out;

  char* p = (char*)d_ws;
  unsigned short* Ut   = (unsigned short*)p; p += (size_t)RR * Nn * 2;      //  4 MB
  unsigned short* Wt   = (unsigned short*)p; p += (size_t)RR * Cc * 2;      //  1 MB
  unsigned short* Vb   = (unsigned short*)p; p += (size_t)UU * RR * 2;      //  4 MB
  float*          p0   = (float*)p;          p += (size_t)2 * Bm * RR * 4;  //  8 MB
  float*          p1   = (float*)p;          p += (size_t)4 * Bm * RR * 4;  // 16 MB
  unsigned short* xus  = (unsigned short*)p; p += (size_t)Bm * RR * 2;      //  2 MB

  // 1) prep: U^T, W^T, V -> bf16 (A-side conversions fused into gemm01)
  prep_kernel<<<3584, 256, 0, stream>>>(U, Ut, W, Wt, V, Vb);

  // 2) merged split-K partials from f32 A: p1[4] = inputs@U, p0[2] = context@W
  gemm01_kernel<<<768, 256, 0, stream>>>(inputs, Ut, context, Wt, p0, p1);

  // 3) xus = bf16((sum p1) * (S + sum p0))
  reduce_mul_kernel<<<Bm * RR / 4 / 256, 256, 0, stream>>>(p1, p0, S, xus, Bm * RR);

  // 4) out = relu(xus @ V^T + bias)   (M=2048, N=4096, K=512, 64x128 tiles)
  gemm2_kernel<<<1024, 256, 0, stream>>>(xus, Vb, bias, out);
}